// Round 2
// baseline (30817.831 us; speedup 1.0000x reference)
//
#include <hip/hip_runtime.h>
#include <hip/hip_bf16.h>

#define BETA 0.125f
#define EPS 1e-5f

// ---------------- cls row init: t[b,0,:] = cls + pos[0,:] ----------------
__global__ __launch_bounds__(256) void cls_k(const float* __restrict__ cls, const float* __restrict__ pos,
                                             float* __restrict__ t){
    int i = blockIdx.x*256 + threadIdx.x;     // 32*768
    int b = i / 768, c = i % 768;
    t[((long)b*197)*768 + c] = cls[c] + pos[c];
}

// ---------------- generic fp32 GEMM ----------------
// C = alpha * opA(A) @ opB(B)  (+= C if ACC), optional RELU.
// AT: A is [K,M]; else [M,K].  BT: B is [N,K]; else [K,N].
// batch z: offset = (z/bdiv)*s1 + (z%bdiv)*s2 per matrix.
template<bool AT, bool BT, bool ACC, bool RELU>
__global__ __launch_bounds__(256) void gemm_k(
    const float* __restrict__ A, int lda, long sA1, long sA2,
    const float* __restrict__ B, int ldb, long sB1, long sB2,
    float* __restrict__ C, int ldc, long sC1, long sC2,
    int M, int N, int K, int bdiv, float alpha)
{
    int z = blockIdx.z;
    A += (long)(z/bdiv)*sA1 + (long)(z%bdiv)*sA2;
    B += (long)(z/bdiv)*sB1 + (long)(z%bdiv)*sB2;
    C += (long)(z/bdiv)*sC1 + (long)(z%bdiv)*sC2;
    __shared__ float As[16][65];
    __shared__ float Bs[16][65];
    const int tid = threadIdx.x;
    const int row0 = blockIdx.y*64, col0 = blockIdx.x*64;
    const int tr = tid>>4, tc = tid&15;
    float acc[4][4] = {};
    for (int k0 = 0; k0 < K; k0 += 16) {
        #pragma unroll
        for (int i=0;i<4;i++){
            int idx = tid + i*256;
            int m, kk;
            if (AT) { m = idx & 63; kk = idx >> 6; }
            else    { kk = idx & 15; m = idx >> 4; }
            int gm = row0+m, gk = k0+kk;
            float v = 0.f;
            if (gm<M && gk<K) v = AT ? A[(long)gk*lda+gm] : A[(long)gm*lda+gk];
            As[kk][m] = v;
        }
        #pragma unroll
        for (int i=0;i<4;i++){
            int idx = tid + i*256;
            int n, kk;
            if (BT) { kk = idx & 15; n = idx >> 4; }
            else    { n = idx & 63; kk = idx >> 6; }
            int gn = col0+n, gk = k0+kk;
            float v = 0.f;
            if (gn<N && gk<K) v = BT ? B[(long)gn*ldb+gk] : B[(long)gk*ldb+gn];
            Bs[kk][n] = v;
        }
        __syncthreads();
        #pragma unroll
        for (int kk=0;kk<16;kk++){
            float a[4], b[4];
            #pragma unroll
            for(int i=0;i<4;i++) a[i] = As[kk][tr*4+i];
            #pragma unroll
            for(int j=0;j<4;j++) b[j] = Bs[kk][tc*4+j];
            #pragma unroll
            for(int i=0;i<4;i++)
                #pragma unroll
                for(int j=0;j<4;j++) acc[i][j] = fmaf(a[i], b[j], acc[i][j]);
        }
        __syncthreads();
    }
    #pragma unroll
    for(int i=0;i<4;i++){
        int r = row0+tr*4+i; if (r>=M) continue;
        #pragma unroll
        for(int j=0;j<4;j++){
            int c = col0+tc*4+j; if (c>=N) continue;
            float v = alpha*acc[i][j];
            if (ACC) v += C[(long)r*ldc+c];
            if (RELU) v = v>0.f ? v : 0.f;
            C[(long)r*ldc+c] = v;
        }
    }
}

// ---------------- encode GEMM: t[b, n+1, :] = x @ w_encT + b_enc + pos[n+1] ----------------
__global__ __launch_bounds__(256) void encode_k(
    const float* __restrict__ X, const float* __restrict__ W,
    const float* __restrict__ be, const float* __restrict__ pos,
    float* __restrict__ T)
{
    __shared__ float As[16][65];
    __shared__ float Bs[16][65];
    const int tid = threadIdx.x;
    const int row0 = blockIdx.y*64, col0 = blockIdx.x*64;
    const int tr = tid>>4, tc = tid&15;
    float acc[4][4] = {};
    for (int k0=0;k0<768;k0+=16){
        #pragma unroll
        for (int i=0;i<4;i++){
            int idx = tid+i*256; int kk=idx&15, m=idx>>4;
            int gm=row0+m;
            As[kk][m] = (gm<6272) ? X[(long)gm*768 + k0+kk] : 0.f;
        }
        #pragma unroll
        for (int i=0;i<4;i++){
            int idx=tid+i*256; int kk=idx&15, n=idx>>4;
            Bs[kk][n] = W[(long)(col0+n)*768 + k0+kk];
        }
        __syncthreads();
        #pragma unroll
        for (int kk=0;kk<16;kk++){
            float a[4], b[4];
            #pragma unroll
            for(int i=0;i<4;i++) a[i]=As[kk][tr*4+i];
            #pragma unroll
            for(int j=0;j<4;j++) b[j]=Bs[kk][tc*4+j];
            #pragma unroll
            for(int i=0;i<4;i++)
                #pragma unroll
                for(int j=0;j<4;j++) acc[i][j] = fmaf(a[i], b[j], acc[i][j]);
        }
        __syncthreads();
    }
    #pragma unroll
    for(int i=0;i<4;i++){
        int r = row0+tr*4+i; if (r>=6272) continue;
        int bb = r/196, n = r%196;
        #pragma unroll
        for(int j=0;j<4;j++){
            int c = col0+tc*4+j;
            float v = acc[i][j] + be[c] + pos[(long)(n+1)*768 + c];
            T[((long)bb*197 + n + 1)*768 + c] = v;
        }
    }
}

// ---------------- decode GEMM: out = G @ w_decT + b_dec ----------------
__global__ __launch_bounds__(256) void decode_k(
    const float* __restrict__ G, const float* __restrict__ W,
    const float* __restrict__ bd, float* __restrict__ out)
{
    __shared__ float As[16][65];
    __shared__ float Bs[16][65];
    const int tid = threadIdx.x;
    const int row0 = blockIdx.y*64, col0 = blockIdx.x*64;
    const int tr = tid>>4, tc = tid&15;
    float acc[4][4] = {};
    for (int k0=0;k0<768;k0+=16){
        #pragma unroll
        for (int i=0;i<4;i++){
            int idx = tid+i*256; int kk=idx&15, m=idx>>4;
            int gm=row0+m;
            As[kk][m] = (gm<6272) ? G[(long)gm*768 + k0+kk] : 0.f;
        }
        #pragma unroll
        for (int i=0;i<4;i++){
            int idx=tid+i*256; int kk=idx&15, n=idx>>4;
            Bs[kk][n] = W[(long)(col0+n)*768 + k0+kk];
        }
        __syncthreads();
        #pragma unroll
        for (int kk=0;kk<16;kk++){
            float a[4], b[4];
            #pragma unroll
            for(int i=0;i<4;i++) a[i]=As[kk][tr*4+i];
            #pragma unroll
            for(int j=0;j<4;j++) b[j]=Bs[kk][tc*4+j];
            #pragma unroll
            for(int i=0;i<4;i++)
                #pragma unroll
                for(int j=0;j<4;j++) acc[i][j] = fmaf(a[i], b[j], acc[i][j]);
        }
        __syncthreads();
    }
    #pragma unroll
    for(int i=0;i<4;i++){
        int r = row0+tr*4+i; if (r>=6272) continue;
        #pragma unroll
        for(int j=0;j<4;j++){
            int c = col0+tc*4+j;
            out[(long)r*768 + c] = acc[i][j] + bd[c];
        }
    }
}

// ---------------- LayerNorm / energy-LN over 768 cols ----------------
// out[r,:] = (x - mu) * rsqrt(mean((x-mu)^2) + eps) * scale + bias
// scalar_scale: scale is a single float; rowmap: read row (r/196)*197 + r%196 + 1 (skip cls)
__global__ __launch_bounds__(256) void ln_k(
    const float* __restrict__ in, float* __restrict__ out,
    const float* __restrict__ scale, const float* __restrict__ bias,
    int scalar_scale, int rowmap)
{
    int r = blockIdx.x;
    long src = rowmap ? ((long)(r/196)*197 + r%196 + 1) : (long)r;
    const float* x = in + src*768;
    int tid = threadIdx.x;
    float v0 = x[tid], v1 = x[tid+256], v2 = x[tid+512];
    __shared__ float red[4];
    float s = v0+v1+v2;
    #pragma unroll
    for (int o=1;o<64;o<<=1) s += __shfl_xor(s, o, 64);
    if ((tid&63)==0) red[tid>>6] = s;
    __syncthreads();
    float mu = (red[0]+red[1]+red[2]+red[3]) * (1.f/768.f);
    float d0=v0-mu, d1=v1-mu, d2=v2-mu;
    float q = d0*d0 + d1*d1 + d2*d2;
    #pragma unroll
    for (int o=1;o<64;o<<=1) q += __shfl_xor(q, o, 64);
    __syncthreads();
    if ((tid&63)==0) red[tid>>6] = q;
    __syncthreads();
    float ms = (red[0]+red[1]+red[2]+red[3]) * (1.f/768.f);
    float inv = rsqrtf(ms + EPS);
    float* o_ = out + (long)r*768;
    float s0 = scalar_scale ? scale[0] : scale[tid];
    float s1 = scalar_scale ? s0 : scale[tid+256];
    float s2 = scalar_scale ? s0 : scale[tid+512];
    o_[tid]     = d0*inv*s0 + bias[tid];
    o_[tid+256] = d1*inv*s1 + bias[tid+256];
    o_[tid+512] = d2*inv*s2 + bias[tid+512];
}

// ---------------- row softmax over L=197, one wave per row ----------------
__global__ __launch_bounds__(256) void softmax_k(float* __restrict__ S, int nrows){
    int row = blockIdx.x*4 + (threadIdx.x>>6);
    if (row >= nrows) return;
    int lane = threadIdx.x & 63;
    float* p = S + (long)row*197;
    float v[4]; float mx = -1e30f;
    #pragma unroll
    for (int i=0;i<4;i++){
        int c = lane + 64*i;
        v[i] = (c<197) ? p[c] : -1e30f;
        mx = fmaxf(mx, v[i]);
    }
    #pragma unroll
    for (int o=1;o<64;o<<=1) mx = fmaxf(mx, __shfl_xor(mx, o, 64));
    float sum = 0.f;
    #pragma unroll
    for (int i=0;i<4;i++){ v[i] = __expf(v[i]-mx); sum += v[i]; }
    #pragma unroll
    for (int o=1;o<64;o<<=1) sum += __shfl_xor(sum, o, 64);
    float invs = 1.f/sum;
    #pragma unroll
    for (int i=0;i<4;i++){
        int c = lane + 64*i;
        if (c<197) p[c] = v[i]*invs;
    }
}

extern "C" void kernel_launch(void* const* d_in, const int* in_sizes, int n_in,
                              void* d_out, int out_size, void* d_ws, size_t ws_size,
                              hipStream_t stream) {
    const float* x       = (const float*)d_in[0];
    const float* w_enc   = (const float*)d_in[1];
    const float* b_enc   = (const float*)d_in[2];
    const float* cls_tok = (const float*)d_in[3];
    const float* pos     = (const float*)d_in[4];
    const float* eln_g   = (const float*)d_in[5];
    const float* eln_b   = (const float*)d_in[6];
    const float* wq      = (const float*)d_in[7];
    const float* wk      = (const float*)d_in[8];
    const float* w_hop   = (const float*)d_in[9];
    const float* dln_w   = (const float*)d_in[10];
    const float* dln_b   = (const float*)d_in[11];
    const float* w_dec   = (const float*)d_in[12];
    const float* b_dec   = (const float*)d_in[13];
    float* out = (float*)d_out;

    const long R = 6304L*768;                // 32*197 rows x 768
    float* t_  = (float*)d_ws;
    float* g_  = t_  + R;
    float* q_  = g_  + R;                    // q; later reused for aq
    float* k_  = q_  + R;
    float* ak_ = k_  + R;
    float* ph_ = ak_ + R;                    // P [384,197,197], then h [6304,3072]
    // total: 5*R + 6304*3072 = 43,573,248 floats = 174.3 MB

    dim3 blk(256);

    cls_k<<<dim3(96), blk, 0, stream>>>(cls_tok, pos, t_);
    encode_k<<<dim3(12,98), blk, 0, stream>>>(x, w_enc, b_enc, pos, t_);

    const long sQ1 = 197L*768, sQ2 = 64;     // per-b, per-h offsets into [6304,768]
    const long sP1 = 12L*38809, sP2 = 38809; // per-b, per-h offsets into P

    for (int step=0; step<12; step++){
        // g = energyLN(t)
        ln_k<<<dim3(6304), blk, 0, stream>>>(t_, g_, eln_g, eln_b, 1, 0);
        // q = g @ wq^T ; k = g @ wk^T    (wq/wk are [768(h*64+z), 768(d)])
        gemm_k<false,true,false,false><<<dim3(12,99,1), blk, 0, stream>>>(
            g_, 768, 0,0, wq, 768, 0,0, q_, 768, 0,0, 6304,768,768, 1, 1.f);
        gemm_k<false,true,false,false><<<dim3(12,99,1), blk, 0, stream>>>(
            g_, 768, 0,0, wk, 768, 0,0, k_, 768, 0,0, 6304,768,768, 1, 1.f);
        // S = beta * q_bh @ k_bh^T   (batched over 384 bh pairs)
        gemm_k<false,true,false,false><<<dim3(4,4,384), blk, 0, stream>>>(
            q_, 768, sQ1,sQ2, k_, 768, sQ1,sQ2, ph_, 197, sP1,sP2, 197,197,64, 12, BETA);
        // P = softmax over last dim
        softmax_k<<<dim3(18912), blk, 0, stream>>>(ph_, 75648);
        // ak = P^T @ q   (must run BEFORE aq overwrites q_)
        gemm_k<true,false,false,false><<<dim3(1,4,384), blk, 0, stream>>>(
            ph_, 197, sP1,sP2, q_, 768, sQ1,sQ2, ak_, 768, sQ1,sQ2, 197,64,197, 12, 1.f);
        // aq = P @ k  -> overwrite q_
        gemm_k<false,false,false,false><<<dim3(1,4,384), blk, 0, stream>>>(
            ph_, 197, sP1,sP2, k_, 768, sQ1,sQ2, q_, 768, sQ1,sQ2, 197,64,197, 12, 1.f);
        // t += aq @ wq ; t += ak @ wk
        gemm_k<false,false,true,false><<<dim3(12,99,1), blk, 0, stream>>>(
            q_, 768, 0,0, wq, 768, 0,0, t_, 768, 0,0, 6304,768,768, 1, 1.f);
        gemm_k<false,false,true,false><<<dim3(12,99,1), blk, 0, stream>>>(
            ak_, 768, 0,0, wk, 768, 0,0, t_, 768, 0,0, 6304,768,768, 1, 1.f);
        // h = relu(g @ w_hop^T)  [6304,3072] ; t += h @ w_hop
        gemm_k<false,true,false,true><<<dim3(48,99,1), blk, 0, stream>>>(
            g_, 768, 0,0, w_hop, 768, 0,0, ph_, 3072, 0,0, 6304,3072,768, 1, 1.f);
        gemm_k<false,false,true,false><<<dim3(12,99,1), blk, 0, stream>>>(
            ph_, 3072, 0,0, w_hop, 768, 0,0, t_, 768, 0,0, 6304,768,3072, 1, 1.f);
    }

    // decode: g = LN(t)[non-cls rows, compacted] ; out = g @ w_dec^T + b_dec
    ln_k<<<dim3(6272), blk, 0, stream>>>(t_, g_, dln_w, dln_b, 0, 1);
    decode_k<<<dim3(12,98), blk, 0, stream>>>(g_, w_dec, b_dec, out);
}

// Round 3
// 5390.286 us; speedup vs baseline: 5.7173x; 5.7173x over previous
//
#include <hip/hip_runtime.h>
#include <hip/hip_bf16.h>

typedef __hip_bfloat16 bf16;
typedef short s8 __attribute__((ext_vector_type(8)));
typedef float f4 __attribute__((ext_vector_type(4)));

#define BETA 0.125f
#define EPS 1e-5f

__device__ __forceinline__ void gld16(const void* g, void* l){
    __builtin_amdgcn_global_load_lds(
        (const __attribute__((address_space(1))) void*)g,
        (__attribute__((address_space(3))) void*)l, 16, 0, 0);
}

// ---------- converts ----------
__global__ __launch_bounds__(256) void f2b_k(const float* __restrict__ in, bf16* __restrict__ out, long n){
    long i = (long)blockIdx.x*256 + threadIdx.x;
    if (i < n) out[i] = __float2bfloat16(in[i]);
}
// x [6272,768] -> bf16 [6400,768] zero-padded rows
__global__ __launch_bounds__(256) void padx_k(const float* __restrict__ x, bf16* __restrict__ xb){
    long i = (long)blockIdx.x*256 + threadIdx.x;
    if (i >= 6400L*768) return;
    long row = i / 768;
    xb[i] = (row < 6272) ? __float2bfloat16(x[i]) : __float2bfloat16(0.f);
}
// B1 [4608,768] bf16 -> B2 [768,4608] bf16 (transpose)
__global__ __launch_bounds__(256) void tr_k(const short* __restrict__ Bi, short* __restrict__ Bo){
    __shared__ short t[32][33];
    int i0 = blockIdx.x*32, j0 = blockIdx.y*32;
    int li = threadIdx.x & 31, lj = threadIdx.x >> 5;   // lj 0..7
    #pragma unroll
    for (int r=0;r<4;r++) t[lj+8*r][li] = Bi[(long)(i0+lj+8*r)*768 + j0+li];
    __syncthreads();
    #pragma unroll
    for (int r=0;r<4;r++) Bo[(long)(j0+lj+8*r)*4608 + i0+li] = t[li][lj+8*r];
}

// ---------- cls row init: t[b,0,:] = cls + pos[0,:] ----------
__global__ __launch_bounds__(256) void cls_k(const float* __restrict__ cls, const float* __restrict__ pos,
                                             float* __restrict__ t){
    int i = blockIdx.x*256 + threadIdx.x;     // 32*768
    int b = i / 768, c = i % 768;
    t[((long)b*197)*768 + c] = cls[c] + pos[c];
}

// ---------- big MFMA GEMM: C = A[M,K] @ B[N,K]^T, bf16 in, fp32 acc ----------
// MODE 0: C bf16 (qkh), relu for col>=relu0
// MODE 1: C fp32 +=  (t accumulate)
// MODE 2: encode epilogue (+b_enc+pos, row remap b*197+n+1, guard row<6272)
// MODE 3: decode epilogue (+bias, guard row<6272)
template<int MODE>
__global__ __launch_bounds__(256) void big_gemm(
    const short* __restrict__ A, int lda,
    const short* __restrict__ B, int ldb,
    float* __restrict__ Cf, bf16* __restrict__ Cb, int ldc,
    int K, int relu0,
    const float* __restrict__ bias, const float* __restrict__ pos)
{
    __shared__ short lsA[4096];   // 128 x 32
    __shared__ short lsB[4096];   // 128 x 32
    const int tid = threadIdx.x;
    const int w = tid>>6, l = tid&63;
    const int m0 = blockIdx.y*128, n0 = blockIdx.x*128;
    const int srow = w*16 + (l>>2);        // 0..63
    const int scol = (l&3)*8;
    const short* pa0 = A + (size_t)(m0+srow)*lda + scol;
    const short* pa1 = A + (size_t)(m0+64+srow)*lda + scol;
    const short* pb0 = B + (size_t)(n0+srow)*ldb + scol;
    const short* pb1 = B + (size_t)(n0+64+srow)*ldb + scol;
    short* la0 = lsA + w*512;
    short* la1 = lsA + 2048 + w*512;
    short* lb0 = lsB + w*512;
    short* lb1 = lsB + 2048 + w*512;
    const int wm = (w>>1)*64, wn = (w&1)*64;
    const int fr = l&15, fq = (l>>4)*8;
    f4 acc[4][4] = {};
    const int nk = K>>5;
    for (int kt=0; kt<nk; kt++){
        gld16(pa0, la0); gld16(pa1, la1);
        gld16(pb0, lb0); gld16(pb1, lb1);
        pa0 += 32; pa1 += 32; pb0 += 32; pb1 += 32;
        __syncthreads();
        s8 af[4], bfr[4];
        #pragma unroll
        for (int i=0;i<4;i++) af[i]  = *(const s8*)(lsA + (wm+i*16+fr)*32 + fq);
        #pragma unroll
        for (int j=0;j<4;j++) bfr[j] = *(const s8*)(lsB + (wn+j*16+fr)*32 + fq);
        #pragma unroll
        for (int i=0;i<4;i++)
            #pragma unroll
            for (int j=0;j<4;j++)
                acc[i][j] = __builtin_amdgcn_mfma_f32_16x16x32_bf16(af[i], bfr[j], acc[i][j], 0,0,0);
        __syncthreads();
    }
    const int er = (l>>4)*4;
    const int ec = l&15;
    #pragma unroll
    for (int i=0;i<4;i++){
        #pragma unroll
        for (int j=0;j<4;j++){
            int gr0 = m0 + wm + i*16 + er;
            int gc  = n0 + wn + j*16 + ec;
            #pragma unroll
            for (int r=0;r<4;r++){
                float v = acc[i][j][r];
                int gr = gr0 + r;
                if (MODE==0){
                    if (gc >= relu0) v = v>0.f ? v : 0.f;
                    Cb[(size_t)gr*ldc + gc] = __float2bfloat16(v);
                } else if (MODE==1){
                    Cf[(size_t)gr*ldc + gc] += v;
                } else if (MODE==2){
                    if (gr < 6272){
                        int b = gr/196, n = gr%196;
                        Cf[((size_t)b*197 + n + 1)*768 + gc] = v + bias[gc] + pos[(long)(n+1)*768+gc];
                    }
                } else {
                    if (gr < 6272) Cf[(size_t)gr*ldc + gc] = v + bias[gc];
                }
            }
        }
    }
}

// ---------- small batched MFMA GEMM (attention) ----------
// C[m,n] = alpha * sum_k opA[m,k] * opB[k,n],  AT: A read transposed; BT: B is [N,K]
// batch z: b=z/12, h=z%12; offsets via (sX1,sX2). C bf16.
template<bool AT, bool BT>
__global__ __launch_bounds__(256) void att_gemm(
    const short* __restrict__ A, long sA1, long sA2, int lda,
    const short* __restrict__ B, long sB1, long sB2, int ldb,
    bf16* __restrict__ C, long sC1, long sC2, int ldc,
    int M, int N, int K, float alpha)
{
    const int z = blockIdx.z, b = z/12, h = z%12;
    A += (long)b*sA1 + (long)h*sA2;
    B += (long)b*sB1 + (long)h*sB2;
    C += (long)b*sC1 + (long)h*sC2;
    __shared__ short sAl[2048];   // 64 x 32
    __shared__ short sBl[2048];
    const int tid = threadIdx.x;
    const int w = tid>>6, l = tid&63;
    const int m0 = blockIdx.y*64, n0 = blockIdx.x*64;
    const int srow = tid>>2, sk = (tid&3)*8;
    const int fr = l&15, fq = (l>>4)*8;
    f4 acc[4] = {};
    for (int k0=0; k0<K; k0+=32){
        #pragma unroll
        for (int e=0;e<8;e++){
            int kk = k0 + sk + e;
            int m = m0 + srow;
            short va = 0;
            if (m < M && kk < K) va = AT ? A[(long)kk*lda + m] : A[(long)m*lda + kk];
            sAl[srow*32 + sk + e] = va;
            int n = n0 + srow;
            short vb = 0;
            if (n < N && kk < K) vb = BT ? B[(long)n*ldb + kk] : B[(long)kk*ldb + n];
            sBl[srow*32 + sk + e] = vb;
        }
        __syncthreads();
        s8 af = *(const s8*)(sAl + (w*16+fr)*32 + fq);
        #pragma unroll
        for (int j=0;j<4;j++){
            s8 bf_ = *(const s8*)(sBl + (j*16+fr)*32 + fq);
            acc[j] = __builtin_amdgcn_mfma_f32_16x16x32_bf16(af, bf_, acc[j], 0,0,0);
        }
        __syncthreads();
    }
    const int er = (l>>4)*4, ec = l&15;
    #pragma unroll
    for (int j=0;j<4;j++){
        int gc = n0 + j*16 + ec;
        if (gc >= N) continue;
        #pragma unroll
        for (int r=0;r<4;r++){
            int gr = m0 + w*16 + er + r;
            if (gr < M) C[(long)gr*ldc + gc] = __float2bfloat16(alpha*acc[j][r]);
        }
    }
}

// ---------- LN: fp32 in -> bf16 out ----------
__global__ __launch_bounds__(256) void ln_k(
    const float* __restrict__ in, bf16* __restrict__ out,
    const float* __restrict__ scale, const float* __restrict__ bias,
    int scalar_scale, int rowmap)
{
    int r = blockIdx.x;
    long src = rowmap ? ((long)(r/196)*197 + r%196 + 1) : (long)r;
    const float* x = in + src*768;
    int tid = threadIdx.x;
    float v0 = x[tid], v1 = x[tid+256], v2 = x[tid+512];
    __shared__ float red[4];
    float s = v0+v1+v2;
    #pragma unroll
    for (int o=1;o<64;o<<=1) s += __shfl_xor(s, o, 64);
    if ((tid&63)==0) red[tid>>6] = s;
    __syncthreads();
    float mu = (red[0]+red[1]+red[2]+red[3]) * (1.f/768.f);
    float d0=v0-mu, d1=v1-mu, d2=v2-mu;
    float q = d0*d0 + d1*d1 + d2*d2;
    #pragma unroll
    for (int o=1;o<64;o<<=1) q += __shfl_xor(q, o, 64);
    __syncthreads();
    if ((tid&63)==0) red[tid>>6] = q;
    __syncthreads();
    float ms = (red[0]+red[1]+red[2]+red[3]) * (1.f/768.f);
    float inv = rsqrtf(ms + EPS);
    bf16* o_ = out + (long)r*768;
    float s0 = scalar_scale ? scale[0] : scale[tid];
    float s1 = scalar_scale ? s0 : scale[tid+256];
    float s2 = scalar_scale ? s0 : scale[tid+512];
    o_[tid]     = __float2bfloat16(d0*inv*s0 + bias[tid]);
    o_[tid+256] = __float2bfloat16(d1*inv*s1 + bias[tid+256]);
    o_[tid+512] = __float2bfloat16(d2*inv*s2 + bias[tid+512]);
}

// ---------- softmax over rows of S (bf16), write P (bf16) ----------
__global__ __launch_bounds__(256) void softmax_k(const bf16* __restrict__ S, bf16* __restrict__ P){
    int row = blockIdx.x*4 + (threadIdx.x>>6);   // 0..75647 (384*197)
    int lane = threadIdx.x & 63;
    long base = (long)row*197;
    float v[4]; float mx = -1e30f;
    #pragma unroll
    for (int i=0;i<4;i++){
        int c = lane + 64*i;
        v[i] = (c<197) ? __bfloat162float(S[base+c]) : -1e30f;
        mx = fmaxf(mx, v[i]);
    }
    #pragma unroll
    for (int o=1;o<64;o<<=1) mx = fmaxf(mx, __shfl_xor(mx, o, 64));
    float sum = 0.f;
    #pragma unroll
    for (int i=0;i<4;i++){ v[i] = __expf(v[i]-mx); sum += v[i]; }
    #pragma unroll
    for (int o=1;o<64;o<<=1) sum += __shfl_xor(sum, o, 64);
    float invs = 1.f/sum;
    #pragma unroll
    for (int i=0;i<4;i++){
        int c = lane + 64*i;
        if (c<197) P[base+c] = __float2bfloat16(v[i]*invs);
    }
}

extern "C" void kernel_launch(void* const* d_in, const int* in_sizes, int n_in,
                              void* d_out, int out_size, void* d_ws, size_t ws_size,
                              hipStream_t stream) {
    const float* x       = (const float*)d_in[0];
    const float* w_enc   = (const float*)d_in[1];
    const float* b_enc   = (const float*)d_in[2];
    const float* cls_tok = (const float*)d_in[3];
    const float* pos     = (const float*)d_in[4];
    const float* eln_g   = (const float*)d_in[5];
    const float* eln_b   = (const float*)d_in[6];
    const float* wq      = (const float*)d_in[7];
    const float* wk      = (const float*)d_in[8];
    const float* w_hop   = (const float*)d_in[9];
    const float* dln_w   = (const float*)d_in[10];
    const float* dln_b   = (const float*)d_in[11];
    const float* w_dec   = (const float*)d_in[12];
    const float* b_dec   = (const float*)d_in[13];
    float* out = (float*)d_out;

    // workspace layout (bytes, all 16B aligned)
    float* t_  = (float*)d_ws;                    // [6400,768] fp32
    bf16* g_   = (bf16*)(t_ + 6400L*768);         // [6400,768]  (also x_bf, also decode y)
    bf16* qkh  = g_ + 6400L*768;                  // [6400,4608] = q|k|h
    bf16* aqak = qkh + 6400L*4608;                // S [384,197,197] then aq|ak [6400,1536]
    bf16* P_   = aqak + 384L*38809;               // [384,197,197]
    bf16* B1   = P_ + 384L*38809;                 // [4608,768]  wq|wk|whop (BT form)
    bf16* B2   = B1 + 4608L*768;                  // [768,4608]  = B1^T
    bf16* we_  = B2 + 768L*4608;                  // [768,768]
    bf16* wd_  = we_ + 768L*768;                  // [768,768]
    // total ~164.6 MB

    dim3 blk(256);

    // one-time weight converts + transpose (run every call; cheap)
    f2b_k<<<dim3((589824+255)/256),  blk, 0, stream>>>(wq,    B1,          589824);
    f2b_k<<<dim3((589824+255)/256),  blk, 0, stream>>>(wk,    B1+589824,   589824);
    f2b_k<<<dim3((2359296+255)/256), blk, 0, stream>>>(w_hop, B1+1179648, 2359296);
    f2b_k<<<dim3((589824+255)/256),  blk, 0, stream>>>(w_enc, we_,         589824);
    f2b_k<<<dim3((589824+255)/256),  blk, 0, stream>>>(w_dec, wd_,         589824);
    tr_k<<<dim3(144,24), blk, 0, stream>>>((const short*)B1, (short*)B2);
    padx_k<<<dim3((int)((6400L*768+255)/256)), blk, 0, stream>>>(x, g_);

    cls_k<<<dim3(96), blk, 0, stream>>>(cls_tok, pos, t_);
    // encode: t = x @ w_enc^T + b_enc + pos  (bf16 MFMA)
    big_gemm<2><<<dim3(6,50), blk, 0, stream>>>((const short*)g_, 768, (const short*)we_, 768,
                                                t_, nullptr, 768, 768, 0, b_enc, pos);

    const long sQ1 = 197L*4608, sQ2 = 64;
    const long sS1 = 12L*38809, sS2 = 38809;
    const long sC1 = 197L*1536, sC2 = 64;

    for (int step=0; step<12; step++){
        ln_k<<<dim3(6304), blk, 0, stream>>>(t_, g_, eln_g, eln_b, 1, 0);
        // [q|k|h] = g @ B1^T  (relu on h cols)
        big_gemm<0><<<dim3(36,50), blk, 0, stream>>>((const short*)g_, 768, (const short*)B1, 768,
                                                     nullptr, qkh, 4608, 768, 1536, nullptr, nullptr);
        // S = beta * q @ k^T  per (b,h)
        att_gemm<false,true><<<dim3(4,4,384), blk, 0, stream>>>(
            (const short*)qkh, sQ1, sQ2, 4608,
            (const short*)(qkh+768), sQ1, sQ2, 4608,
            aqak, sS1, sS2, 197, 197, 197, 64, BETA);
        // P = softmax(S)
        softmax_k<<<dim3(18912), blk, 0, stream>>>(aqak, P_);
        // aq = P @ k  -> aqak cols [h*64, h*64+64)
        att_gemm<false,false><<<dim3(1,4,384), blk, 0, stream>>>(
            (const short*)P_, sS1, sS2, 197,
            (const short*)(qkh+768), sQ1, sQ2, 4608,
            aqak, sC1, sC2, 1536, 197, 64, 197, 1.f);
        // ak = P^T @ q -> aqak cols [768+h*64, ...)
        att_gemm<true,false><<<dim3(1,4,384), blk, 0, stream>>>(
            (const short*)P_, sS1, sS2, 197,
            (const short*)qkh, sQ1, sQ2, 4608,
            aqak+768, sC1, sC2, 1536, 197, 64, 197, 1.f);
        // t += [aq|ak] @ [wq;wk]   (B2 cols 0..1535)
        big_gemm<1><<<dim3(6,50), blk, 0, stream>>>((const short*)aqak, 1536, (const short*)B2, 4608,
                                                    t_, nullptr, 768, 1536, 0, nullptr, nullptr);
        // t += h @ whop            (B2 cols 1536..4607)
        big_gemm<1><<<dim3(6,50), blk, 0, stream>>>((const short*)(qkh+1536), 4608, (const short*)(B2+1536), 4608,
                                                    t_, nullptr, 768, 3072, 0, nullptr, nullptr);
    }

    // decode
    ln_k<<<dim3(6272), blk, 0, stream>>>(t_, g_, dln_w, dln_b, 0, 1);
    big_gemm<3><<<dim3(6,50), blk, 0, stream>>>((const short*)g_, 768, (const short*)wd_, 768,
                                                out, nullptr, 768, 768, 0, b_dec, nullptr);
}

// Round 4
// 3340.064 us; speedup vs baseline: 9.2267x; 1.6138x over previous
//
#include <hip/hip_runtime.h>
#include <hip/hip_bf16.h>

typedef __hip_bfloat16 bf16;
typedef short s8 __attribute__((ext_vector_type(8)));
typedef short sv4 __attribute__((ext_vector_type(4)));
typedef float f4 __attribute__((ext_vector_type(4)));

#define BETA 0.125f
#define EPS 1e-5f

__device__ __forceinline__ void gld16(const void* g, void* l){
    __builtin_amdgcn_global_load_lds(
        (const __attribute__((address_space(1))) void*)g,
        (__attribute__((address_space(3))) void*)l, 16, 0, 0);
}

// ---------- converts ----------
__global__ __launch_bounds__(256) void f2b_k(const float* __restrict__ in, bf16* __restrict__ out, long n){
    long i = (long)blockIdx.x*256 + threadIdx.x;
    if (i < n) out[i] = __float2bfloat16(in[i]);
}
// x [6272,768] -> bf16 [6400,768] zero-padded rows
__global__ __launch_bounds__(256) void padx_k(const float* __restrict__ x, bf16* __restrict__ xb){
    long i = (long)blockIdx.x*256 + threadIdx.x;
    if (i >= 6400L*768) return;
    long row = i / 768;
    xb[i] = (row < 6272) ? __float2bfloat16(x[i]) : __float2bfloat16(0.f);
}
// B1 [4608,768] bf16 -> B2 [768,4608] bf16 (transpose)
__global__ __launch_bounds__(256) void tr_k(const short* __restrict__ Bi, short* __restrict__ Bo){
    __shared__ short t[32][33];
    int i0 = blockIdx.x*32, j0 = blockIdx.y*32;
    int li = threadIdx.x & 31, lj = threadIdx.x >> 5;
    #pragma unroll
    for (int r=0;r<4;r++) t[lj+8*r][li] = Bi[(long)(i0+lj+8*r)*768 + j0+li];
    __syncthreads();
    #pragma unroll
    for (int r=0;r<4;r++) Bo[(long)(j0+lj+8*r)*4608 + i0+li] = t[li][lj+8*r];
}

// ---------- cls row init ----------
__global__ __launch_bounds__(256) void cls_k(const float* __restrict__ cls, const float* __restrict__ pos,
                                             float* __restrict__ t){
    int i = blockIdx.x*256 + threadIdx.x;
    int b = i / 768, c = i % 768;
    t[((long)b*197)*768 + c] = cls[c] + pos[c];
}

// ---------- big MFMA GEMM: C = A[M,K] @ B[N,K]^T ----------
// MODE 0: C bf16, relu for col>=relu0 | MODE 1: C fp32 += | MODE 2: encode | MODE 3: decode
template<int MODE>
__global__ __launch_bounds__(256) void big_gemm(
    const short* __restrict__ A, int lda,
    const short* __restrict__ B, int ldb,
    float* __restrict__ Cf, bf16* __restrict__ Cb, int ldc,
    int K, int relu0,
    const float* __restrict__ bias, const float* __restrict__ pos)
{
    __shared__ short lsA[4096];
    __shared__ short lsB[4096];
    const int tid = threadIdx.x;
    const int w = tid>>6, l = tid&63;
    const int m0 = blockIdx.y*128, n0 = blockIdx.x*128;
    const int srow = w*16 + (l>>2);
    const int scol = (l&3)*8;
    const short* pa0 = A + (size_t)(m0+srow)*lda + scol;
    const short* pa1 = A + (size_t)(m0+64+srow)*lda + scol;
    const short* pb0 = B + (size_t)(n0+srow)*ldb + scol;
    const short* pb1 = B + (size_t)(n0+64+srow)*ldb + scol;
    short* la0 = lsA + w*512;
    short* la1 = lsA + 2048 + w*512;
    short* lb0 = lsB + w*512;
    short* lb1 = lsB + 2048 + w*512;
    const int wm = (w>>1)*64, wn = (w&1)*64;
    const int fr = l&15, fq = (l>>4)*8;
    f4 acc[4][4] = {};
    const int nk = K>>5;
    for (int kt=0; kt<nk; kt++){
        gld16(pa0, la0); gld16(pa1, la1);
        gld16(pb0, lb0); gld16(pb1, lb1);
        pa0 += 32; pa1 += 32; pb0 += 32; pb1 += 32;
        __syncthreads();
        s8 af[4], bfr[4];
        #pragma unroll
        for (int i=0;i<4;i++) af[i]  = *(const s8*)(lsA + (wm+i*16+fr)*32 + fq);
        #pragma unroll
        for (int j=0;j<4;j++) bfr[j] = *(const s8*)(lsB + (wn+j*16+fr)*32 + fq);
        #pragma unroll
        for (int i=0;i<4;i++)
            #pragma unroll
            for (int j=0;j<4;j++)
                acc[i][j] = __builtin_amdgcn_mfma_f32_16x16x32_bf16(af[i], bfr[j], acc[i][j], 0,0,0);
        __syncthreads();
    }
    const int er = (l>>4)*4;
    const int ec = l&15;
    #pragma unroll
    for (int i=0;i<4;i++){
        #pragma unroll
        for (int j=0;j<4;j++){
            int gr0 = m0 + wm + i*16 + er;
            int gc  = n0 + wn + j*16 + ec;
            #pragma unroll
            for (int r=0;r<4;r++){
                float v = acc[i][j][r];
                int gr = gr0 + r;
                if (MODE==0){
                    if (gc >= relu0) v = v>0.f ? v : 0.f;
                    Cb[(size_t)gr*ldc + gc] = __float2bfloat16(v);
                } else if (MODE==1){
                    Cf[(size_t)gr*ldc + gc] += v;
                } else if (MODE==2){
                    if (gr < 6272){
                        int b = gr/196, n = gr%196;
                        Cf[((size_t)b*197 + n + 1)*768 + gc] = v + bias[gc] + pos[(long)(n+1)*768+gc];
                    }
                } else {
                    if (gr < 6272) Cf[(size_t)gr*ldc + gc] = v + bias[gc];
                }
            }
        }
    }
}

// ---------- pack q^T / k^T : [384][64 z][256 m] bf16, zero-padded ----------
__global__ __launch_bounds__(256) void pack_k(const short* __restrict__ qkh,
                                              short* __restrict__ qT, short* __restrict__ kT){
    __shared__ short tq[64][65];
    __shared__ short tk[64][65];
    const int bh = blockIdx.x, b = bh/12, h = bh%12;
    const int mc = blockIdx.y*64;
    const int tid = threadIdx.x;
    #pragma unroll
    for (int e=0;e<16;e++){
        int i = tid + e*256; int r = i>>6, c = i&63;
        int mg = mc + r;
        short vq = 0, vk = 0;
        if (mg < 197){
            size_t base = (size_t)(b*197+mg)*4608 + h*64 + c;
            vq = qkh[base]; vk = qkh[base+768];
        }
        tq[r][c] = vq; tk[r][c] = vk;
    }
    __syncthreads();
    #pragma unroll
    for (int e=0;e<16;e++){
        int i = tid + e*256; int zr = i>>6, cm = i&63;
        size_t o = (size_t)bh*16384 + (size_t)zr*256 + mc + cm;
        qT[o] = tq[cm][zr];
        kT[o] = tk[cm][zr];
    }
}

// ---------- fused attention per (b,h): S=beta*q@k^T, P=softmax, aq=P@k, ak=P^T@q ----------
// Writes aq into qkh q-columns and ak into qkh k-columns (rows < 197 of this b).
__global__ __launch_bounds__(256) void attn_k(
    short* __restrict__ qkh, const short* __restrict__ qT, const short* __restrict__ kT)
{
    __shared__ short Pl[64*232];     // P natural [m_local][n], stride 232 (bank-spread, 16B-aligned rows)
    __shared__ short Ptl[208*72];    // P^T [n][m_local], stride 72
    const int bh = blockIdx.x, b = bh/12, h = bh%12;
    const int tid = threadIdx.x, w = tid>>6, l = tid&63;
    const int lr = l&15, lq = l>>4;
    const size_t qcol = (size_t)h*64, kcol = 768 + qcol;
    const size_t rbase = (size_t)b*197*4608;
    const short* qTp = qT + (size_t)bh*16384;
    const short* kTp = kT + (size_t)bh*16384;

    // zero P pad cols 208..223 (read by aq k-step 6)
    for (int i=tid; i<64*16; i+=256){ int r=i>>4, c=208+(i&15); Pl[r*232+c]=0; }

    f4 ak[13];
    #pragma unroll
    for (int t=0;t<13;t++) ak[t] = (f4){0.f,0.f,0.f,0.f};

    for (int iter=0; iter<4; iter++){
        const int m0 = iter*64;
        // ---- S: this wave owns m-rows [w*16, w*16+16) local; 13 col-tiles ----
        f4 S[13];
        #pragma unroll
        for (int t=0;t<13;t++) S[t] = (f4){0.f,0.f,0.f,0.f};
        const int mrow = m0 + w*16 + lr;
        #pragma unroll
        for (int ks=0; ks<2; ks++){
            s8 af = *(const s8*)(qkh + rbase + (size_t)mrow*4608 + qcol + ks*32 + lq*8);
            #pragma unroll
            for (int t=0;t<13;t++){
                s8 bf = *(const s8*)(qkh + rbase + (size_t)(t*16+lr)*4608 + kcol + ks*32 + lq*8);
                S[t] = __builtin_amdgcn_mfma_f32_16x16x32_bf16(af, bf, S[t], 0,0,0);
            }
        }
        // guard: all waves done reading Pl/Ptl of previous iter (and zero-init visible)
        __syncthreads();
        // ---- softmax: lane holds rows mbase..mbase+3 (local), one col per tile ----
        const int mbase = w*16 + lq*4;
        #pragma unroll
        for (int r=0;r<4;r++){
            float mx = -1e30f;
            #pragma unroll
            for (int t=0;t<13;t++){
                float v = S[t][r]*BETA;
                if (t==12 && lr>=5) v = -1e30f;   // cols 197..207 masked
                S[t][r] = v;
                mx = fmaxf(mx, v);
            }
            mx = fmaxf(mx, __shfl_xor(mx,1,64)); mx = fmaxf(mx, __shfl_xor(mx,2,64));
            mx = fmaxf(mx, __shfl_xor(mx,4,64)); mx = fmaxf(mx, __shfl_xor(mx,8,64));
            float sm = 0.f;
            #pragma unroll
            for (int t=0;t<13;t++){ float e = __expf(S[t][r]-mx); S[t][r]=e; sm+=e; }
            sm += __shfl_xor(sm,1,64); sm += __shfl_xor(sm,2,64);
            sm += __shfl_xor(sm,4,64); sm += __shfl_xor(sm,8,64);
            float inv = 1.f/sm;
            bool valid = (m0 + mbase + r) < 197;   // garbage rows -> P=0
            #pragma unroll
            for (int t=0;t<13;t++) S[t][r] = valid ? S[t][r]*inv : 0.f;
        }
        // ---- store P natural + transposed ----
        #pragma unroll
        for (int t=0;t<13;t++){
            int c = t*16 + lr;
            short pb[4];
            #pragma unroll
            for (int r=0;r<4;r++){
                bf16 bv = __float2bfloat16(S[t][r]);
                pb[r] = *(short*)&bv;
                Pl[(mbase+r)*232 + c] = pb[r];
            }
            *(sv4*)(Ptl + c*72 + mbase) = (sv4){pb[0],pb[1],pb[2],pb[3]};
        }
        __syncthreads();
        // ---- aq^T = kT(A) x P(B): C[z, m_local]; wave owns z-rows [w*16,..) ----
        f4 aq[4];
        #pragma unroll
        for (int t=0;t<4;t++) aq[t] = (f4){0.f,0.f,0.f,0.f};
        #pragma unroll
        for (int ks=0; ks<7; ks++){
            s8 af = *(const s8*)(kTp + (w*16+lr)*256 + ks*32 + lq*8);
            #pragma unroll
            for (int mt=0;mt<4;mt++){
                s8 bf = *(const s8*)(Pl + (mt*16+lr)*232 + ks*32 + lq*8);
                aq[mt] = __builtin_amdgcn_mfma_f32_16x16x32_bf16(af, bf, aq[mt], 0,0,0);
            }
        }
        // write aq: row m (col = lr of tile), cols h*64 + z (4 consecutive z = regs)
        #pragma unroll
        for (int mt=0;mt<4;mt++){
            int mg = m0 + mt*16 + lr;
            if (mg < 197){
                sv4 pv;
                #pragma unroll
                for (int r=0;r<4;r++){ bf16 bv=__float2bfloat16(aq[mt][r]); pv[r]=*(short*)&bv; }
                *(sv4*)(qkh + rbase + (size_t)mg*4608 + qcol + w*16 + lq*4) = pv;
            }
        }
        // ---- ak += Pt(A) x qT(B): C[n, z]; wave owns z-cols [w*16,..) ----
        #pragma unroll
        for (int ks=0; ks<2; ks++){
            s8 bf = *(const s8*)(qTp + (w*16+lr)*256 + m0 + ks*32 + lq*8);
            #pragma unroll
            for (int t=0;t<13;t++){
                s8 af = *(const s8*)(Ptl + (t*16+lr)*72 + ks*32 + lq*8);
                ak[t] = __builtin_amdgcn_mfma_f32_16x16x32_bf16(af, bf, ak[t], 0,0,0);
            }
        }
    }
    // ---- write ak: row n, col 768 + h*64 + w*16 + lr ----
    #pragma unroll
    for (int t=0;t<13;t++){
        #pragma unroll
        for (int r=0;r<4;r++){
            int n = t*16 + lq*4 + r;
            if (n < 197)
                *(bf16*)(qkh + rbase + (size_t)n*4608 + kcol + w*16 + lr) = __float2bfloat16(ak[t][r]);
        }
    }
}

// ---------- LN: fp32 in -> bf16 out ----------
__global__ __launch_bounds__(256) void ln_k(
    const float* __restrict__ in, bf16* __restrict__ out,
    const float* __restrict__ scale, const float* __restrict__ bias,
    int scalar_scale, int rowmap)
{
    int r = blockIdx.x;
    long src = rowmap ? ((long)(r/196)*197 + r%196 + 1) : (long)r;
    const float* x = in + src*768;
    int tid = threadIdx.x;
    float v0 = x[tid], v1 = x[tid+256], v2 = x[tid+512];
    __shared__ float red[4];
    float s = v0+v1+v2;
    #pragma unroll
    for (int o=1;o<64;o<<=1) s += __shfl_xor(s, o, 64);
    if ((tid&63)==0) red[tid>>6] = s;
    __syncthreads();
    float mu = (red[0]+red[1]+red[2]+red[3]) * (1.f/768.f);
    float d0=v0-mu, d1=v1-mu, d2=v2-mu;
    float q = d0*d0 + d1*d1 + d2*d2;
    #pragma unroll
    for (int o=1;o<64;o<<=1) q += __shfl_xor(q, o, 64);
    __syncthreads();
    if ((tid&63)==0) red[tid>>6] = q;
    __syncthreads();
    float ms = (red[0]+red[1]+red[2]+red[3]) * (1.f/768.f);
    float inv = rsqrtf(ms + EPS);
    bf16* o_ = out + (long)r*768;
    float s0 = scalar_scale ? scale[0] : scale[tid];
    float s1 = scalar_scale ? s0 : scale[tid+256];
    float s2 = scalar_scale ? s0 : scale[tid+512];
    o_[tid]     = __float2bfloat16(d0*inv*s0 + bias[tid]);
    o_[tid+256] = __float2bfloat16(d1*inv*s1 + bias[tid+256]);
    o_[tid+512] = __float2bfloat16(d2*inv*s2 + bias[tid+512]);
}

extern "C" void kernel_launch(void* const* d_in, const int* in_sizes, int n_in,
                              void* d_out, int out_size, void* d_ws, size_t ws_size,
                              hipStream_t stream) {
    const float* x       = (const float*)d_in[0];
    const float* w_enc   = (const float*)d_in[1];
    const float* b_enc   = (const float*)d_in[2];
    const float* cls_tok = (const float*)d_in[3];
    const float* pos     = (const float*)d_in[4];
    const float* eln_g   = (const float*)d_in[5];
    const float* eln_b   = (const float*)d_in[6];
    const float* wq      = (const float*)d_in[7];
    const float* wk      = (const float*)d_in[8];
    const float* w_hop   = (const float*)d_in[9];
    const float* dln_w   = (const float*)d_in[10];
    const float* dln_b   = (const float*)d_in[11];
    const float* w_dec   = (const float*)d_in[12];
    const float* b_dec   = (const float*)d_in[13];
    float* out = (float*)d_out;

    float* t_  = (float*)d_ws;                    // [6400,768] fp32
    bf16* g_   = (bf16*)(t_ + 6400L*768);         // [6400,768]
    bf16* qkh  = g_ + 6400L*768;                  // [6400,4608] = q|k|h (aq|ak overwrite q|k)
    bf16* qT   = qkh + 6400L*4608;                // [384,64,256]
    bf16* kT   = qT + 384L*16384;                 // [384,64,256]
    bf16* B1   = kT + 384L*16384;                 // [4608,768]  wq|wk|whop
    bf16* B2   = B1 + 4608L*768;                  // [768,4608]  = B1^T
    bf16* we_  = B2 + 768L*4608;                  // [768,768]
    bf16* wd_  = we_ + 768L*768;                  // [768,768]
    // total ~130 MB

    dim3 blk(256);

    f2b_k<<<dim3((589824+255)/256),  blk, 0, stream>>>(wq,    B1,          589824);
    f2b_k<<<dim3((589824+255)/256),  blk, 0, stream>>>(wk,    B1+589824,   589824);
    f2b_k<<<dim3((2359296+255)/256), blk, 0, stream>>>(w_hop, B1+1179648, 2359296);
    f2b_k<<<dim3((589824+255)/256),  blk, 0, stream>>>(w_enc, we_,         589824);
    f2b_k<<<dim3((589824+255)/256),  blk, 0, stream>>>(w_dec, wd_,         589824);
    tr_k<<<dim3(144,24), blk, 0, stream>>>((const short*)B1, (short*)B2);
    padx_k<<<dim3((int)((6400L*768+255)/256)), blk, 0, stream>>>(x, g_);

    cls_k<<<dim3(96), blk, 0, stream>>>(cls_tok, pos, t_);
    big_gemm<2><<<dim3(6,50), blk, 0, stream>>>((const short*)g_, 768, (const short*)we_, 768,
                                                t_, nullptr, 768, 768, 0, b_enc, pos);

    for (int step=0; step<12; step++){
        ln_k<<<dim3(6304), blk, 0, stream>>>(t_, g_, eln_g, eln_b, 1, 0);
        // [q|k|h] = g @ B1^T  (relu on h cols)
        big_gemm<0><<<dim3(36,50), blk, 0, stream>>>((const short*)g_, 768, (const short*)B1, 768,
                                                     nullptr, qkh, 4608, 768, 1536, nullptr, nullptr);
        // transposed padded copies of q,k
        pack_k<<<dim3(384,4), blk, 0, stream>>>((const short*)qkh, (short*)qT, (short*)kT);
        // fused attention; writes aq|ak into qkh cols 0..1535
        attn_k<<<dim3(384), blk, 0, stream>>>((short*)qkh, (const short*)qT, (const short*)kT);
        // t += [aq|ak|h] @ B2^T   (single K=4608 GEMM)
        big_gemm<1><<<dim3(6,50), blk, 0, stream>>>((const short*)qkh, 4608, (const short*)B2, 4608,
                                                    t_, nullptr, 768, 4608, 0, nullptr, nullptr);
    }

    ln_k<<<dim3(6272), blk, 0, stream>>>(t_, g_, dln_w, dln_b, 0, 1);
    big_gemm<3><<<dim3(6,50), blk, 0, stream>>>((const short*)g_, 768, (const short*)wd_, 768,
                                                out, nullptr, 768, 768, 0, b_dec, nullptr);
}